// Round 2
// baseline (8602.677 us; speedup 1.0000x reference)
//
#include <hip/hip_runtime.h>
#include <math.h>

// Problem constants (from reference)
#define BB    64
#define SS    512
#define HH    256
#define HH2   512
#define G4    1024   // 4*H
#define TMAXX 513    // S+1
#define NTOP  5
#define EPSF  1e-7f

__device__ __forceinline__ float sigmoidf_(float v) { return 1.f / (1.f + expf(-v)); }

// Pack W_hh (4H x H, row-major) into [kb][j] float4 layout so that the GEMV
// inner loop load Wp[kb*1024 + j] is coalesced across threads j.
// Also zero h_old row 0 for every batch (ws is poisoned 0xAA before each call).
__global__ void init_kernel(const float* __restrict__ Whh_f, const float* __restrict__ Whh_b,
                            float4* __restrict__ Wp_f, float4* __restrict__ Wp_b,
                            float* __restrict__ h_old) {
  int tid = blockIdx.x * blockDim.x + threadIdx.x;
  if (tid < 2 * 64 * 1024) {
    int m  = tid >> 16;      // 0 = forward cell, 1 = backward cell
    int r  = tid & 65535;
    int kb = r >> 10;        // k-block (4 consecutive k)
    int j  = r & 1023;       // gate/output row
    const float* src = m ? Whh_b : Whh_f;
    const float* p = src + j * HH + kb * 4;
    float4 v = make_float4(p[0], p[1], p[2], p[3]);
    (m ? Wp_b : Wp_f)[r] = v;
  }
  if (tid < BB * HH2) {
    int b = tid >> 9;
    int e = tid & 511;
    h_old[(size_t)b * TMAXX * HH2 + e] = 0.f;
  }
}

// One block per batch row; 1024 threads; 512 sequential steps.
__global__ __launch_bounds__(1024)
void bilstm_kernel(const float* __restrict__ x,
                   const float* __restrict__ wih_f, const float* __restrict__ bias_f,
                   const float* __restrict__ wih_b, const float* __restrict__ bias_b,
                   const float* __restrict__ w_t,
                   const float4* __restrict__ Wp_f, const float4* __restrict__ Wp_b,
                   float* __restrict__ h_old, float* __restrict__ out) {
  const int b   = blockIdx.x;
  const int tid = threadIdx.x;

  __shared__ float  sh_x[SS];
  __shared__ float4 sh_hf4[HH / 4];   // h_f (read as float4 broadcast in GEMV)
  __shared__ float4 sh_hb4[HH / 4];   // h_b
  __shared__ float  sh_cf[HH], sh_cb[HH];
  __shared__ float  sh_gf[G4], sh_gb[G4];
  __shared__ float  sh_hcomb[HH2];
  __shared__ float  sh_red[HH2];
  __shared__ float  sh_w1[HH2], sh_w2[HH2];
  __shared__ float  sh_tw[TMAXX];     // cached th_old[t] . w2
  __shared__ float  sh_t5v[NTOP];     // running top-5 of tw (descending)
  __shared__ int    sh_t5i[NTOP];
  __shared__ float  sh_s1, sh_tw5, sh_invsum;
  __shared__ float  sh_wk[4];
  __shared__ int    sh_ik[4];

  if (tid < SS) sh_x[tid] = x[b * SS + tid];
  if (tid < HH2) { sh_w1[tid] = w_t[tid]; sh_w2[tid] = w_t[HH2 + tid]; }
  if (tid < HH) {
    ((float*)sh_hf4)[tid] = 0.f;  ((float*)sh_hb4)[tid] = 0.f;
    sh_cf[tid] = 0.f;  sh_cb[tid] = 0.f;
  }
  if (tid == 0) { sh_tw[0] = 0.f; sh_t5v[0] = 0.f; sh_t5i[0] = 0; }
  const float wfi = wih_f[tid], bfv = bias_f[tid];
  const float wbi = wih_b[tid], bbv = bias_b[tid];
  float* hob = h_old + (size_t)b * TMAXX * HH2;
  int t5cnt = 1;   // meaningful on thread 0 only
  __syncthreads();

  for (int i = 0; i < SS; ++i) {
    // ---------- phase 1: gate GEMV (each thread owns one gate row of each cell) ----
    float accf = fmaf(sh_x[i], wfi, bfv);
    float accb = fmaf(sh_x[SS - 1 - i], wbi, bbv);
#pragma unroll 8
    for (int kb = 0; kb < HH / 4; ++kb) {
      float4 w4 = Wp_f[(kb << 10) + tid];
      float4 h4 = sh_hf4[kb];
      accf = fmaf(w4.x, h4.x, accf); accf = fmaf(w4.y, h4.y, accf);
      accf = fmaf(w4.z, h4.z, accf); accf = fmaf(w4.w, h4.w, accf);
    }
#pragma unroll 8
    for (int kb = 0; kb < HH / 4; ++kb) {
      float4 w4 = Wp_b[(kb << 10) + tid];
      float4 h4 = sh_hb4[kb];
      accb = fmaf(w4.x, h4.x, accb); accb = fmaf(w4.y, h4.y, accb);
      accb = fmaf(w4.z, h4.z, accb); accb = fmaf(w4.w, h4.w, accb);
    }
    sh_gf[tid] = accf; sh_gb[tid] = accb;
    __syncthreads();

    // ---------- phase 2: LSTM cell update + score partial products ----------------
    if (tid < HH2) {
      const int   e = tid & (HH - 1);
      const float* g = (tid < HH) ? sh_gf : sh_gb;
      const float c_old = (tid < HH) ? sh_cf[e] : sh_cb[e];
      float ig = sigmoidf_(g[e]);
      float fg = sigmoidf_(g[HH + e]);
      float gg = tanhf(g[2 * HH + e]);
      float og = sigmoidf_(g[3 * HH + e]);
      float cn = fg * c_old + ig * gg;
      float hn = og * tanhf(cn);
      if (tid < HH) { sh_cf[e] = cn; ((float*)sh_hf4)[e] = hn; }
      else          { sh_cb[e] = cn; ((float*)sh_hb4)[e] = hn; }
      sh_hcomb[tid] = hn;
      sh_red[tid]   = tanhf(hn) * sh_w1[tid];
    }
    __syncthreads();

    // ---------- phase 3: s1 = tanh(h_comb).w1 (wave 0) + sparse weights (thread 0) -
    if (tid < 64) {
      float v = 0.f;
#pragma unroll
      for (int k = 0; k < 8; ++k) v += sh_red[tid + (k << 6)];
      for (int off = 32; off > 0; off >>= 1) v += __shfl_down(v, off);
      if (tid == 0) {
        sh_s1 = v;
        if (i >= NTOP) {   // rs = i+1 > TOPK  -> sparse path
          float tw5 = sh_t5v[4];          // 5th largest tw == 5th largest s - s1
          float rk[4]; float rsum = 0.f;
#pragma unroll
          for (int k = 0; k < 4; ++k) {
            float r = sh_t5v[k] - tw5 - EPSF;
            rk[k] = r > 0.f ? r : 0.f;
            rsum += rk[k];
          }
          float inv = 1.f / (rsum + EPSF);
#pragma unroll
          for (int k = 0; k < 4; ++k) { sh_wk[k] = rk[k] * inv; sh_ik[k] = sh_t5i[k]; }
          sh_tw5 = tw5; sh_invsum = inv;
        }
      }
    }
    __syncthreads();

    // ---------- phase 4: attention context + h_new + th.w2 partials ---------------
    if (tid < HH2) {
      float acc = 0.f;
      if (i >= NTOP) {
        // at most 4 positions can exceed delta = 5th + eps
#pragma unroll
        for (int k = 0; k < 4; ++k) {
          float w = sh_wk[k];
          if (w > 0.f) acc = fmaf(w, hob[(size_t)sh_ik[k] * HH2 + tid], acc);
        }
      } else {
        // rs <= TOPK: raw (unnormalized) scores as weights; h_old[0] == 0
        float s1 = sh_s1;
        for (int t = 1; t <= i; ++t)
          acc = fmaf(s1 + sh_tw[t], hob[(size_t)t * HH2 + tid], acc);
      }
      float hnew = sh_hcomb[tid] + acc;
      hob[(size_t)(i + 1) * HH2 + tid] = hnew;
      sh_red[tid] = tanhf(hnew) * sh_w2[tid];
      if (i == SS - 1) {
        out[b * HH2 + tid] = acc;                       // output 0: final attn_c
        float r = sh_tw[tid] - sh_tw5 - EPSF;           // output 1: final attn_w[:S]
        out[BB * HH2 + b * SS + tid] = (r > 0.f) ? r * sh_invsum : 0.f;
      }
    }
    __syncthreads();

    // ---------- phase 5: tw[i+1] = tanh(h_new).w2 ; insert into running top-5 -----
    if (tid < 64) {
      float v = 0.f;
#pragma unroll
      for (int k = 0; k < 8; ++k) v += sh_red[tid + (k << 6)];
      for (int off = 32; off > 0; off >>= 1) v += __shfl_down(v, off);
      if (tid == 0) {
        int idx = i + 1;
        sh_tw[idx] = v;
        if (t5cnt < NTOP) {
          int p = t5cnt++;
          sh_t5v[p] = v; sh_t5i[p] = idx;
          while (p > 0 && sh_t5v[p] > sh_t5v[p - 1]) {
            float tv = sh_t5v[p]; sh_t5v[p] = sh_t5v[p - 1]; sh_t5v[p - 1] = tv;
            int   ti = sh_t5i[p]; sh_t5i[p] = sh_t5i[p - 1]; sh_t5i[p - 1] = ti;
            --p;
          }
        } else if (v > sh_t5v[4]) {
          sh_t5v[4] = v; sh_t5i[4] = idx;
          int p = 4;
          while (p > 0 && sh_t5v[p] > sh_t5v[p - 1]) {
            float tv = sh_t5v[p]; sh_t5v[p] = sh_t5v[p - 1]; sh_t5v[p - 1] = tv;
            int   ti = sh_t5i[p]; sh_t5i[p] = sh_t5i[p - 1]; sh_t5i[p - 1] = ti;
            --p;
          }
        }
      }
    }
    __syncthreads();
  }
}

extern "C" void kernel_launch(void* const* d_in, const int* in_sizes, int n_in,
                              void* d_out, int out_size, void* d_ws, size_t ws_size,
                              hipStream_t stream) {
  const float* x     = (const float*)d_in[0];
  const float* Wih_f = (const float*)d_in[1];
  const float* Whh_f = (const float*)d_in[2];
  const float* b_f   = (const float*)d_in[3];
  const float* Wih_b = (const float*)d_in[4];
  const float* Whh_b = (const float*)d_in[5];
  const float* b_b   = (const float*)d_in[6];
  const float* w_t   = (const float*)d_in[7];
  float* out = (float*)d_out;

  char* ws = (char*)d_ws;
  float4* Wp_f  = (float4*)ws;                       // 1 MB
  float4* Wp_b  = (float4*)(ws + (1 << 20));         // 1 MB
  float*  h_old = (float*)(ws + (2 << 20));          // B*513*512*4 ≈ 64.1 MB

  init_kernel<<<512, 256, 0, stream>>>(Whh_f, Whh_b, Wp_f, Wp_b, h_old);
  bilstm_kernel<<<BB, 1024, 0, stream>>>(x, Wih_f, b_f, Wih_b, b_b, w_t,
                                         Wp_f, Wp_b, h_old, out);
}